// Round 10
// baseline (3040.457 us; speedup 1.0000x reference)
//
#include <hip/hip_runtime.h>
#include <cstdint>
#include <cstddef>

#define D_MODEL 512
#define NHEAD   8
#define DH      64
#define B_SZ    4
#define L_SEQ   2048
#define U_TOP   38          // int(5*ln(2048)) = 38
#define QPB     8           // queries per attention block
#define KT      128         // key tile staged in LDS

// monotone float<->uint mapping (order-preserving, exact)
__device__ __forceinline__ unsigned mapmono(float f) {
    unsigned u = __float_as_uint(f);
    return (u & 0x80000000u) ? ~u : (u | 0x80000000u);
}

// ---------------- fp32 GEMM: C(8192x512) = A @ W + b ----------------
// Accurate tiled version for V and the output projection (order-insensitive).
// MODE 0: C row-major (b,l,dm)   MODE 1: scatter to (b,h,l,d)
template<int MODE>
__global__ __launch_bounds__(256)
void gemm512(const float* __restrict__ A, const float* __restrict__ W,
             const float* __restrict__ bias, float* __restrict__ C)
{
    __shared__ float As[16][68];
    __shared__ float Bs[16][68];
    const int tid  = threadIdx.x;
    const int row0 = blockIdx.x * 64;
    const int col0 = blockIdx.y * 64;
    const int ty = tid >> 4, tx = tid & 15;
    float acc[4][4] = {};

    for (int kt = 0; kt < D_MODEL; kt += 16) {
        {
            const int m = tid >> 2, k = (tid & 3) << 2;
            const float4 a = *reinterpret_cast<const float4*>(
                &A[(size_t)(row0 + m) * D_MODEL + kt + k]);
            As[k + 0][m] = a.x; As[k + 1][m] = a.y;
            As[k + 2][m] = a.z; As[k + 3][m] = a.w;
        }
        {
            const int k = tid >> 4, n = (tid & 15) << 2;
            *reinterpret_cast<float4*>(&Bs[k][n]) =
                *reinterpret_cast<const float4*>(
                    &W[(size_t)(kt + k) * D_MODEL + col0 + n]);
        }
        __syncthreads();
        #pragma unroll
        for (int kk = 0; kk < 16; ++kk) {
            const float4 a4 = *reinterpret_cast<const float4*>(&As[kk][ty << 2]);
            const float4 b4 = *reinterpret_cast<const float4*>(&Bs[kk][tx << 2]);
            const float av[4] = {a4.x, a4.y, a4.z, a4.w};
            const float bv[4] = {b4.x, b4.y, b4.z, b4.w};
            #pragma unroll
            for (int i = 0; i < 4; ++i)
                #pragma unroll
                for (int j = 0; j < 4; ++j)
                    acc[i][j] += av[i] * bv[j];
        }
        __syncthreads();
    }

    #pragma unroll
    for (int i = 0; i < 4; ++i) {
        const int r = row0 + (ty << 2) + i;
        const int cb = col0 + (tx << 2);
        float4 v;
        v.x = acc[i][0] + bias[cb + 0];
        v.y = acc[i][1] + bias[cb + 1];
        v.z = acc[i][2] + bias[cb + 2];
        v.w = acc[i][3] + bias[cb + 3];
        if (MODE == 0) {
            *reinterpret_cast<float4*>(&C[(size_t)r * D_MODEL + cb]) = v;
        } else {
            const int b = r >> 11, l = r & (L_SEQ - 1);
            const int h = cb >> 6, d = cb & 63;
            *reinterpret_cast<float4*>(
                &C[(size_t)((b * NHEAD + h) * L_SEQ + l) * DH + d]) = v;
        }
    }
}

// ----- np-replica GEMM for Q,K: SINGLE K-panel sequential FMA chain -----
// (LOCKED arithmetic — this passed round 9. Per C element: ONE fp32
// accumulator, FMA over k=0..511 ascending, then one fp32 bias add.)
__global__ __launch_bounds__(256)
void chain_gemm_qk(const float* __restrict__ x, const float* __restrict__ W,
                   const float* __restrict__ bias, float* __restrict__ Out)
{
    const int tid  = threadIdx.x;
    const int col  = blockIdx.y * 256 + tid;        // 0..511
    const int row0 = blockIdx.x * 16;               // 16 rows per block

    float acc[16];
    #pragma unroll
    for (int r = 0; r < 16; ++r) acc[r] = 0.f;

    for (int k = 0; k < D_MODEL; k += 4) {          // one panel: k = 0..511
        const float w0 = W[(size_t)(k + 0) * D_MODEL + col];
        const float w1 = W[(size_t)(k + 1) * D_MODEL + col];
        const float w2 = W[(size_t)(k + 2) * D_MODEL + col];
        const float w3 = W[(size_t)(k + 3) * D_MODEL + col];
        #pragma unroll
        for (int r = 0; r < 16; ++r) {
            const float4 xv = *reinterpret_cast<const float4*>(
                &x[(size_t)(row0 + r) * D_MODEL + k]);
            acc[r] = __fmaf_rn(xv.x, w0, acc[r]);
            acc[r] = __fmaf_rn(xv.y, w1, acc[r]);
            acc[r] = __fmaf_rn(xv.z, w2, acc[r]);
            acc[r] = __fmaf_rn(xv.w, w3, acc[r]);
        }
    }

    const float bc = bias[col];
    const int h = col >> 6, d = col & 63;
    #pragma unroll
    for (int r = 0; r < 16; ++r) {
        const int row = row0 + r;
        const int b = row >> 11, l = row & (L_SEQ - 1);
        Out[((size_t)((b * NHEAD + h) * L_SEQ + l)) * DH + d] =
            __fadd_rn(acc[r], bc);
    }
}

// ---- attention: BLAS-chain scores (LOCKED bits) -> exact fp32 top-38 ----
// Perf changes vs round 9 (arithmetic identical):
//  * Ks XOR-swizzled, stride 64 (was 68): kills the 8-way bank conflict
//  * Q via per-lane register + v_readlane broadcast (no LDS read, no hoist)
//  * __launch_bounds__(256,4): VGPR<=128 -> 4 blocks/CU (was 1)
__global__ __launch_bounds__(256, 4)
void attn_kernel(const float* __restrict__ Q, const float* __restrict__ K,
                 const float* __restrict__ V, float* __restrict__ ctx)
{
    __shared__ float Ks[KT * DH];          // 32 KB, swizzled: elem =
                                           //  r*64 + (col ^ ((r&7)<<2))
    __shared__ int   kidx[QPB][64];        // 2 KB  kept keys (ascending)
    __shared__ float kwgt[QPB][64];        // 2 KB  kept exp-weights

    // XCD swizzle: all 256 q-tiles of a (b,h) on one XCD (K/V L2-resident)
    const int bid = blockIdx.x;
    const int xcd = bid & 7, jrem = bid >> 3;
    const int bh  = xcd * 4 + (jrem >> 8);   // 0..31
    const int qt  = jrem & 255;              // 0..255
    const int b   = bh >> 3, h = bh & 7;

    const float* __restrict__ Qbh = Q + (size_t)bh * L_SEQ * DH;
    const float* __restrict__ Kbh = K + (size_t)bh * L_SEQ * DH;
    const float* __restrict__ Vbh = V + (size_t)bh * L_SEQ * DH;

    const int tid = threadIdx.x;
    const int wave = tid >> 6, lane = tid & 63;
    const int q0 = wave * 2;

    // Q held distributed: lane d holds Q[q][d]; broadcast via v_readlane
    const float Qr0 = Qbh[(size_t)(qt * QPB + q0) * DH + lane];
    const float Qr1 = Qbh[(size_t)(qt * QPB + q0 + 1) * DH + lane];

    float s[2][32];

    #pragma unroll
    for (int t = 0; t < L_SEQ / KT; ++t) {        // 16 tiles, fully unrolled
        __syncthreads();
        #pragma unroll
        for (int c = 0; c < 8; ++c) {             // stage K tile, swizzled
            const int f = c * 1024 + tid * 4;
            const int r = f >> 6, col = f & 63;
            const int sidx = (r << 6) + (col ^ ((r & 7) << 2));
            *reinterpret_cast<float4*>(&Ks[sidx]) =
                *reinterpret_cast<const float4*>(&Kbh[(size_t)t * (KT * DH) + f]);
        }
        __syncthreads();

        // single FMA chain over d ascending per (q,key) — LOCKED order
        float v00 = 0.f, v01 = 0.f, v10 = 0.f, v11 = 0.f;
        #pragma unroll
        for (int dc = 0; dc < 16; ++dc) {
            const int sw = (dc ^ (lane & 7)) << 2;
            const float4 k0 = *reinterpret_cast<const float4*>(
                &Ks[(lane << 6) + sw]);
            const float4 k1 = *reinterpret_cast<const float4*>(
                &Ks[((64 + lane) << 6) + sw]);
            const float q00 = __uint_as_float(__builtin_amdgcn_readlane(__float_as_uint(Qr0), 4 * dc + 0));
            const float q01 = __uint_as_float(__builtin_amdgcn_readlane(__float_as_uint(Qr0), 4 * dc + 1));
            const float q02 = __uint_as_float(__builtin_amdgcn_readlane(__float_as_uint(Qr0), 4 * dc + 2));
            const float q03 = __uint_as_float(__builtin_amdgcn_readlane(__float_as_uint(Qr0), 4 * dc + 3));
            const float q10 = __uint_as_float(__builtin_amdgcn_readlane(__float_as_uint(Qr1), 4 * dc + 0));
            const float q11 = __uint_as_float(__builtin_amdgcn_readlane(__float_as_uint(Qr1), 4 * dc + 1));
            const float q12 = __uint_as_float(__builtin_amdgcn_readlane(__float_as_uint(Qr1), 4 * dc + 2));
            const float q13 = __uint_as_float(__builtin_amdgcn_readlane(__float_as_uint(Qr1), 4 * dc + 3));
            v00 = __fmaf_rn(q00, k0.x, v00);
            v00 = __fmaf_rn(q01, k0.y, v00);
            v00 = __fmaf_rn(q02, k0.z, v00);
            v00 = __fmaf_rn(q03, k0.w, v00);
            v01 = __fmaf_rn(q00, k1.x, v01);
            v01 = __fmaf_rn(q01, k1.y, v01);
            v01 = __fmaf_rn(q02, k1.z, v01);
            v01 = __fmaf_rn(q03, k1.w, v01);
            v10 = __fmaf_rn(q10, k0.x, v10);
            v10 = __fmaf_rn(q11, k0.y, v10);
            v10 = __fmaf_rn(q12, k0.z, v10);
            v10 = __fmaf_rn(q13, k0.w, v10);
            v11 = __fmaf_rn(q10, k1.x, v11);
            v11 = __fmaf_rn(q11, k1.y, v11);
            v11 = __fmaf_rn(q12, k1.z, v11);
            v11 = __fmaf_rn(q13, k1.w, v11);
        }
        // /sqrt(64) = *0.125, exact
        s[0][2*t]     = __fmul_rn(v00, 0.125f);
        s[0][2*t + 1] = __fmul_rn(v01, 0.125f);
        s[1][2*t]     = __fmul_rn(v10, 0.125f);
        s[1][2*t + 1] = __fmul_rn(v11, 0.125f);
    }

    #pragma unroll
    for (int q = 0; q < 2; ++q) {
        const int qg = q0 + q;

        // map scores to monotone uint space (in place)
        #pragma unroll
        for (int j2 = 0; j2 < 32; ++j2)
            s[q][j2] = __uint_as_float(mapmono(s[q][j2]));

        // exact fp32 38th-largest: binary search in mapped-uint space.
        unsigned long long lo = 0ull, hi = 0x100000000ull;
        while (hi - lo > 1ull) {
            const unsigned mid = (unsigned)((lo + hi) >> 1);
            int cnt = 0;
            #pragma unroll
            for (int j2 = 0; j2 < 32; ++j2)
                cnt += (__float_as_uint(s[q][j2]) >= mid) ? 1 : 0;
            #pragma unroll
            for (int off = 32; off; off >>= 1) cnt += __shfl_xor(cnt, off);
            if (cnt >= U_TOP) lo = mid; else hi = mid;
        }
        const unsigned thrU = (unsigned)lo;     // mapped bits of the 38th value

        // row max in mapped space (top-1 always kept)
        unsigned um = 0u;
        #pragma unroll
        for (int j2 = 0; j2 < 32; ++j2) {
            const unsigned ub = __float_as_uint(s[q][j2]);
            um = um > ub ? um : ub;
        }
        #pragma unroll
        for (int off = 32; off; off >>= 1) {
            const unsigned o = (unsigned)__shfl_xor((int)um, off);
            um = um > o ? um : o;
        }
        const float mrow = __uint_as_float((um & 0x80000000u) ? (um & 0x7FFFFFFFu) : ~um);

        // compact kept keys (ascending key order) via ballot prefix-sum
        int base = 0; float lsum = 0.f;
        #pragma unroll
        for (int j2 = 0; j2 < 32; ++j2) {
            const unsigned ub = __float_as_uint(s[q][j2]);
            const bool keep = (ub >= thrU);     // == !(score < thr), np semantics
            const unsigned long long mk = __ballot(keep);
            if (keep) {
                const float sc = __uint_as_float((ub & 0x80000000u) ? (ub & 0x7FFFFFFFu) : ~ub);
                const float w = __expf(sc - mrow);
                const int pos = base + (int)__popcll(mk & ((1ull << lane) - 1ull));
                if (pos < 64) {
                    kidx[qg][pos] = ((j2 >> 1) << 7) + ((j2 & 1) << 6) + lane;
                    kwgt[qg][pos] = w;
                }
                lsum += w;
            }
            base += (int)__popcll(mk);
        }
        #pragma unroll
        for (int off = 32; off; off >>= 1) lsum += __shfl_xor(lsum, off);
        const int nk = base < 64 ? base : 64;

        // ctx[d] = (sum over kept, ascending key order) w * V[k][d] / Z
        float acc = 0.f;
        for (int i = 0; i < nk; ++i)
            acc = __fmaf_rn(kwgt[qg][i], Vbh[(size_t)kidx[qg][i] * DH + lane], acc);
        acc /= lsum;

        const int l = qt * QPB + qg;
        ctx[((size_t)(b * L_SEQ + l)) * D_MODEL + h * DH + lane] = acc;
    }
}

extern "C" void kernel_launch(void* const* d_in, const int* in_sizes, int n_in,
                              void* d_out, int out_size, void* d_ws, size_t ws_size,
                              hipStream_t stream) {
    (void)in_sizes; (void)n_in; (void)out_size; (void)ws_size;
    const float* x  = (const float*)d_in[0];
    const float* Wq = (const float*)d_in[1];
    const float* bq = (const float*)d_in[2];
    const float* Wk = (const float*)d_in[3];
    const float* bk = (const float*)d_in[4];
    const float* Wv = (const float*)d_in[5];
    const float* bv = (const float*)d_in[6];
    const float* Wo = (const float*)d_in[7];
    const float* bo = (const float*)d_in[8];
    float* out = (float*)d_out;

    // ws: Qf | Kf | V | ctx = 4 x 16.78 MB = 67.1 MB
    const size_t NE = (size_t)B_SZ * NHEAD * L_SEQ * DH;   // 4.19e6
    float* Qf = (float*)d_ws;
    float* Kf = Qf + NE;
    float* Vw = Kf + NE;
    float* Cw = Vw + NE;

    const dim3 gq(512, 2), g(128, 8), blk(256);
    chain_gemm_qk<<<gq, blk, 0, stream>>>(x, Wq, bq, Qf);
    chain_gemm_qk<<<gq, blk, 0, stream>>>(x, Wk, bk, Kf);
    gemm512<1>   <<<g,  blk, 0, stream>>>(x, Wv, bv, Vw);
    attn_kernel  <<<dim3(8192), blk, 0, stream>>>(Qf, Kf, Vw, Cw);
    gemm512<0>   <<<g,  blk, 0, stream>>>(Cw, Wo, bo, out);
}

// Round 12
// 1805.194 us; speedup vs baseline: 1.6843x; 1.6843x over previous
//
#include <hip/hip_runtime.h>
#include <cstdint>
#include <cstddef>

#define D_MODEL 512
#define NHEAD   8
#define DH      64
#define B_SZ    4
#define L_SEQ   2048
#define U_TOP   38          // int(5*ln(2048)) = 38
#define QPB     8           // queries per attention block
#define KT      128         // key tile staged in LDS

// monotone float<->uint mapping (order-preserving, exact)
__device__ __forceinline__ unsigned mapmono(float f) {
    unsigned u = __float_as_uint(f);
    return (u & 0x80000000u) ? ~u : (u | 0x80000000u);
}

// ---------------- fp32 GEMM: C(8192x512) = A @ W + b ----------------
// Accurate tiled version for V and the output projection (order-insensitive).
// MODE 0: C row-major (b,l,dm)   MODE 1: scatter to (b,h,l,d)
template<int MODE>
__global__ __launch_bounds__(256)
void gemm512(const float* __restrict__ A, const float* __restrict__ W,
             const float* __restrict__ bias, float* __restrict__ C)
{
    __shared__ float As[16][68];
    __shared__ float Bs[16][68];
    const int tid  = threadIdx.x;
    const int row0 = blockIdx.x * 64;
    const int col0 = blockIdx.y * 64;
    const int ty = tid >> 4, tx = tid & 15;
    float acc[4][4] = {};

    for (int kt = 0; kt < D_MODEL; kt += 16) {
        {
            const int m = tid >> 2, k = (tid & 3) << 2;
            const float4 a = *reinterpret_cast<const float4*>(
                &A[(size_t)(row0 + m) * D_MODEL + kt + k]);
            As[k + 0][m] = a.x; As[k + 1][m] = a.y;
            As[k + 2][m] = a.z; As[k + 3][m] = a.w;
        }
        {
            const int k = tid >> 4, n = (tid & 15) << 2;
            *reinterpret_cast<float4*>(&Bs[k][n]) =
                *reinterpret_cast<const float4*>(
                    &W[(size_t)(kt + k) * D_MODEL + col0 + n]);
        }
        __syncthreads();
        #pragma unroll
        for (int kk = 0; kk < 16; ++kk) {
            const float4 a4 = *reinterpret_cast<const float4*>(&As[kk][ty << 2]);
            const float4 b4 = *reinterpret_cast<const float4*>(&Bs[kk][tx << 2]);
            const float av[4] = {a4.x, a4.y, a4.z, a4.w};
            const float bv[4] = {b4.x, b4.y, b4.z, b4.w};
            #pragma unroll
            for (int i = 0; i < 4; ++i)
                #pragma unroll
                for (int j = 0; j < 4; ++j)
                    acc[i][j] += av[i] * bv[j];
        }
        __syncthreads();
    }

    #pragma unroll
    for (int i = 0; i < 4; ++i) {
        const int r = row0 + (ty << 2) + i;
        const int cb = col0 + (tx << 2);
        float4 v;
        v.x = acc[i][0] + bias[cb + 0];
        v.y = acc[i][1] + bias[cb + 1];
        v.z = acc[i][2] + bias[cb + 2];
        v.w = acc[i][3] + bias[cb + 3];
        if (MODE == 0) {
            *reinterpret_cast<float4*>(&C[(size_t)r * D_MODEL + cb]) = v;
        } else {
            const int b = r >> 11, l = r & (L_SEQ - 1);
            const int h = cb >> 6, d = cb & 63;
            *reinterpret_cast<float4*>(
                &C[(size_t)((b * NHEAD + h) * L_SEQ + l) * DH + d]) = v;
        }
    }
}

// ----- np-replica GEMM for Q,K: SINGLE K-panel sequential FMA chain -----
// (LOCKED arithmetic — passed round 9. Per C element: ONE fp32 accumulator,
// FMA over k=0..511 ascending, then one fp32 bias add.)
__global__ __launch_bounds__(256)
void chain_gemm_qk(const float* __restrict__ x, const float* __restrict__ W,
                   const float* __restrict__ bias, float* __restrict__ Out)
{
    const int tid  = threadIdx.x;
    const int col  = blockIdx.y * 256 + tid;        // 0..511
    const int row0 = blockIdx.x * 16;               // 16 rows per block

    float acc[16];
    #pragma unroll
    for (int r = 0; r < 16; ++r) acc[r] = 0.f;

    for (int k = 0; k < D_MODEL; k += 4) {          // one panel: k = 0..511
        const float w0 = W[(size_t)(k + 0) * D_MODEL + col];
        const float w1 = W[(size_t)(k + 1) * D_MODEL + col];
        const float w2 = W[(size_t)(k + 2) * D_MODEL + col];
        const float w3 = W[(size_t)(k + 3) * D_MODEL + col];
        #pragma unroll
        for (int r = 0; r < 16; ++r) {
            const float4 xv = *reinterpret_cast<const float4*>(
                &x[(size_t)(row0 + r) * D_MODEL + k]);
            acc[r] = __fmaf_rn(xv.x, w0, acc[r]);
            acc[r] = __fmaf_rn(xv.y, w1, acc[r]);
            acc[r] = __fmaf_rn(xv.z, w2, acc[r]);
            acc[r] = __fmaf_rn(xv.w, w3, acc[r]);
        }
    }

    const float bc = bias[col];
    const int h = col >> 6, d = col & 63;
    #pragma unroll
    for (int r = 0; r < 16; ++r) {
        const int row = row0 + r;
        const int b = row >> 11, l = row & (L_SEQ - 1);
        Out[((size_t)((b * NHEAD + h) * L_SEQ + l)) * DH + d] =
            __fadd_rn(acc[r], bc);
    }
}

// ---- attention: BLAS-chain scores (LOCKED bits) -> exact fp32 top-38 ----
// Perf deltas vs round 10:
//  * __launch_bounds__(256,2): VGPR cap 128 (need ~110) -> NO SPILL
//    (round 10's (256,4) allocated 64 VGPR and spilled s[64] -> 4.8 GB
//    of scratch writes per dispatch; that was the whole regression)
//  * Q back in LDS (wave-uniform float4 broadcast reads; frees VALU
//    issue slots vs 2048 v_readlanes)
//  * K tile keeps the stride-64 XOR-swizzle layout (proven r10)
__global__ __launch_bounds__(256, 2)
void attn_kernel(const float* __restrict__ Q, const float* __restrict__ K,
                 const float* __restrict__ V, float* __restrict__ ctx)
{
    __shared__ float Qs[QPB][DH];          // 2 KB
    __shared__ float Ks[KT * DH];          // 32 KB, elem = r*64 + (col ^ ((r&7)<<2))
    __shared__ int   kidx[QPB][64];        // 2 KB  kept keys (ascending)
    __shared__ float kwgt[QPB][64];        // 2 KB  kept exp-weights

    // XCD swizzle: all 256 q-tiles of a (b,h) on one XCD (K/V L2-resident)
    const int bid = blockIdx.x;
    const int xcd = bid & 7, jrem = bid >> 3;
    const int bh  = xcd * 4 + (jrem >> 8);   // 0..31
    const int qt  = jrem & 255;              // 0..255
    const int b   = bh >> 3, h = bh & 7;

    const float* __restrict__ Qbh = Q + (size_t)bh * L_SEQ * DH;
    const float* __restrict__ Kbh = K + (size_t)bh * L_SEQ * DH;
    const float* __restrict__ Vbh = V + (size_t)bh * L_SEQ * DH;

    const int tid = threadIdx.x;
    const int wave = tid >> 6, lane = tid & 63;
    const int q0 = wave * 2;

    {   // stage Q tile (8x64)
        const int q = tid >> 5, d0 = (tid & 31) << 1;
        *reinterpret_cast<float2*>(&Qs[q][d0]) =
            *reinterpret_cast<const float2*>(&Qbh[(size_t)(qt * QPB + q) * DH + d0]);
    }

    float s[2][32];

    #pragma unroll
    for (int t = 0; t < L_SEQ / KT; ++t) {        // 16 tiles, fully unrolled
        __syncthreads();
        #pragma unroll
        for (int c = 0; c < 8; ++c) {             // stage K tile, swizzled
            const int f = c * 1024 + tid * 4;
            const int r = f >> 6, col = f & 63;
            const int sidx = (r << 6) + (col ^ ((r & 7) << 2));
            *reinterpret_cast<float4*>(&Ks[sidx]) =
                *reinterpret_cast<const float4*>(&Kbh[(size_t)t * (KT * DH) + f]);
        }
        __syncthreads();

        // single FMA chain over d ascending per (q,key) — LOCKED order
        float v00 = 0.f, v01 = 0.f, v10 = 0.f, v11 = 0.f;
        #pragma unroll
        for (int dc = 0; dc < 16; ++dc) {
            const int sw = (dc ^ (lane & 7)) << 2;   // logical cols 4dc..4dc+3
            const float4 k0 = *reinterpret_cast<const float4*>(
                &Ks[(lane << 6) + sw]);
            const float4 k1 = *reinterpret_cast<const float4*>(
                &Ks[((64 + lane) << 6) + sw]);
            const float4 p0 = *reinterpret_cast<const float4*>(&Qs[q0][dc << 2]);
            const float4 p1 = *reinterpret_cast<const float4*>(&Qs[q0 + 1][dc << 2]);
            v00 = __fmaf_rn(p0.x, k0.x, v00);
            v00 = __fmaf_rn(p0.y, k0.y, v00);
            v00 = __fmaf_rn(p0.z, k0.z, v00);
            v00 = __fmaf_rn(p0.w, k0.w, v00);
            v01 = __fmaf_rn(p0.x, k1.x, v01);
            v01 = __fmaf_rn(p0.y, k1.y, v01);
            v01 = __fmaf_rn(p0.z, k1.z, v01);
            v01 = __fmaf_rn(p0.w, k1.w, v01);
            v10 = __fmaf_rn(p1.x, k0.x, v10);
            v10 = __fmaf_rn(p1.y, k0.y, v10);
            v10 = __fmaf_rn(p1.z, k0.z, v10);
            v10 = __fmaf_rn(p1.w, k0.w, v10);
            v11 = __fmaf_rn(p1.x, k1.x, v11);
            v11 = __fmaf_rn(p1.y, k1.y, v11);
            v11 = __fmaf_rn(p1.z, k1.z, v11);
            v11 = __fmaf_rn(p1.w, k1.w, v11);
        }
        // /sqrt(64) = *0.125, exact
        s[0][2*t]     = __fmul_rn(v00, 0.125f);
        s[0][2*t + 1] = __fmul_rn(v01, 0.125f);
        s[1][2*t]     = __fmul_rn(v10, 0.125f);
        s[1][2*t + 1] = __fmul_rn(v11, 0.125f);
    }

    #pragma unroll
    for (int q = 0; q < 2; ++q) {
        const int qg = q0 + q;

        // map scores to monotone uint space (in place)
        #pragma unroll
        for (int j2 = 0; j2 < 32; ++j2)
            s[q][j2] = __uint_as_float(mapmono(s[q][j2]));

        // exact fp32 38th-largest: binary search in mapped-uint space.
        unsigned long long lo = 0ull, hi = 0x100000000ull;
        while (hi - lo > 1ull) {
            const unsigned mid = (unsigned)((lo + hi) >> 1);
            int cnt = 0;
            #pragma unroll
            for (int j2 = 0; j2 < 32; ++j2)
                cnt += (__float_as_uint(s[q][j2]) >= mid) ? 1 : 0;
            #pragma unroll
            for (int off = 32; off; off >>= 1) cnt += __shfl_xor(cnt, off);
            if (cnt >= U_TOP) lo = mid; else hi = mid;
        }
        const unsigned thrU = (unsigned)lo;     // mapped bits of the 38th value

        // row max in mapped space (top-1 always kept)
        unsigned um = 0u;
        #pragma unroll
        for (int j2 = 0; j2 < 32; ++j2) {
            const unsigned ub = __float_as_uint(s[q][j2]);
            um = um > ub ? um : ub;
        }
        #pragma unroll
        for (int off = 32; off; off >>= 1) {
            const unsigned o = (unsigned)__shfl_xor((int)um, off);
            um = um > o ? um : o;
        }
        const float mrow = __uint_as_float((um & 0x80000000u) ? (um & 0x7FFFFFFFu) : ~um);

        // compact kept keys (ascending key order) via ballot prefix-sum
        int base = 0; float lsum = 0.f;
        #pragma unroll
        for (int j2 = 0; j2 < 32; ++j2) {
            const unsigned ub = __float_as_uint(s[q][j2]);
            const bool keep = (ub >= thrU);     // == !(score < thr), np semantics
            const unsigned long long mk = __ballot(keep);
            if (keep) {
                const float sc = __uint_as_float((ub & 0x80000000u) ? (ub & 0x7FFFFFFFu) : ~ub);
                const float w = __expf(sc - mrow);
                const int pos = base + (int)__popcll(mk & ((1ull << lane) - 1ull));
                if (pos < 64) {
                    kidx[qg][pos] = ((j2 >> 1) << 7) + ((j2 & 1) << 6) + lane;
                    kwgt[qg][pos] = w;
                }
                lsum += w;
            }
            base += (int)__popcll(mk);
        }
        #pragma unroll
        for (int off = 32; off; off >>= 1) lsum += __shfl_xor(lsum, off);
        const int nk = base < 64 ? base : 64;

        // ctx[d] = (sum over kept, ascending key order) w * V[k][d] / Z
        float acc = 0.f;
        for (int i = 0; i < nk; ++i)
            acc = __fmaf_rn(kwgt[qg][i], Vbh[(size_t)kidx[qg][i] * DH + lane], acc);
        acc /= lsum;

        const int l = qt * QPB + qg;
        ctx[((size_t)(b * L_SEQ + l)) * D_MODEL + h * DH + lane] = acc;
    }
}

extern "C" void kernel_launch(void* const* d_in, const int* in_sizes, int n_in,
                              void* d_out, int out_size, void* d_ws, size_t ws_size,
                              hipStream_t stream) {
    (void)in_sizes; (void)n_in; (void)out_size; (void)ws_size;
    const float* x  = (const float*)d_in[0];
    const float* Wq = (const float*)d_in[1];
    const float* bq = (const float*)d_in[2];
    const float* Wk = (const float*)d_in[3];
    const float* bk = (const float*)d_in[4];
    const float* Wv = (const float*)d_in[5];
    const float* bv = (const float*)d_in[6];
    const float* Wo = (const float*)d_in[7];
    const float* bo = (const float*)d_in[8];
    float* out = (float*)d_out;

    // ws: Qf | Kf | V | ctx = 4 x 16.78 MB = 67.1 MB
    const size_t NE = (size_t)B_SZ * NHEAD * L_SEQ * DH;   // 4.19e6
    float* Qf = (float*)d_ws;
    float* Kf = Qf + NE;
    float* Vw = Kf + NE;
    float* Cw = Vw + NE;

    const dim3 gq(512, 2), g(128, 8), blk(256);
    chain_gemm_qk<<<gq, blk, 0, stream>>>(x, Wq, bq, Qf);
    chain_gemm_qk<<<gq, blk, 0, stream>>>(x, Wk, bk, Kf);
    gemm512<1>   <<<g,  blk, 0, stream>>>(x, Wv, bv, Vw);
    attn_kernel  <<<dim3(8192), blk, 0, stream>>>(Qf, Kf, Vw, Cw);
    gemm512<0>   <<<g,  blk, 0, stream>>>(Cw, Wo, bo, out);
}

// Round 14
// 1211.940 us; speedup vs baseline: 2.5088x; 1.4895x over previous
//
#include <hip/hip_runtime.h>
#include <cstdint>
#include <cstddef>

#define D_MODEL 512
#define NHEAD   8
#define DH      64
#define B_SZ    4
#define L_SEQ   2048
#define U_TOP   38          // int(5*ln(2048)) = 38
#define QPB     8           // queries per attention block (1 per wave)
#define KT      128         // key tile staged in LDS

// monotone float<->uint mapping (order-preserving, exact)
__device__ __forceinline__ unsigned mapmono(float f) {
    unsigned u = __float_as_uint(f);
    return (u & 0x80000000u) ? ~u : (u | 0x80000000u);
}

// ---------------- fp32 GEMM: C(8192x512) = A @ W + b ----------------
// Accurate tiled version for V and the output projection (order-insensitive).
// MODE 0: C row-major (b,l,dm)   MODE 1: scatter to (b,h,l,d)
template<int MODE>
__global__ __launch_bounds__(256)
void gemm512(const float* __restrict__ A, const float* __restrict__ W,
             const float* __restrict__ bias, float* __restrict__ C)
{
    __shared__ float As[16][68];
    __shared__ float Bs[16][68];
    const int tid  = threadIdx.x;
    const int row0 = blockIdx.x * 64;
    const int col0 = blockIdx.y * 64;
    const int ty = tid >> 4, tx = tid & 15;
    float acc[4][4] = {};

    for (int kt = 0; kt < D_MODEL; kt += 16) {
        {
            const int m = tid >> 2, k = (tid & 3) << 2;
            const float4 a = *reinterpret_cast<const float4*>(
                &A[(size_t)(row0 + m) * D_MODEL + kt + k]);
            As[k + 0][m] = a.x; As[k + 1][m] = a.y;
            As[k + 2][m] = a.z; As[k + 3][m] = a.w;
        }
        {
            const int k = tid >> 4, n = (tid & 15) << 2;
            *reinterpret_cast<float4*>(&Bs[k][n]) =
                *reinterpret_cast<const float4*>(
                    &W[(size_t)(kt + k) * D_MODEL + col0 + n]);
        }
        __syncthreads();
        #pragma unroll
        for (int kk = 0; kk < 16; ++kk) {
            const float4 a4 = *reinterpret_cast<const float4*>(&As[kk][ty << 2]);
            const float4 b4 = *reinterpret_cast<const float4*>(&Bs[kk][tx << 2]);
            const float av[4] = {a4.x, a4.y, a4.z, a4.w};
            const float bv[4] = {b4.x, b4.y, b4.z, b4.w};
            #pragma unroll
            for (int i = 0; i < 4; ++i)
                #pragma unroll
                for (int j = 0; j < 4; ++j)
                    acc[i][j] += av[i] * bv[j];
        }
        __syncthreads();
    }

    #pragma unroll
    for (int i = 0; i < 4; ++i) {
        const int r = row0 + (ty << 2) + i;
        const int cb = col0 + (tx << 2);
        float4 v;
        v.x = acc[i][0] + bias[cb + 0];
        v.y = acc[i][1] + bias[cb + 1];
        v.z = acc[i][2] + bias[cb + 2];
        v.w = acc[i][3] + bias[cb + 3];
        if (MODE == 0) {
            *reinterpret_cast<float4*>(&C[(size_t)r * D_MODEL + cb]) = v;
        } else {
            const int b = r >> 11, l = r & (L_SEQ - 1);
            const int h = cb >> 6, d = cb & 63;
            *reinterpret_cast<float4*>(
                &C[(size_t)((b * NHEAD + h) * L_SEQ + l) * DH + d]) = v;
        }
    }
}

// ----- np-replica GEMM for Q,K: SINGLE K-panel sequential FMA chain -----
// (LOCKED arithmetic — passed round 9. Per C element: ONE fp32 accumulator,
// FMA over k=0..511 ascending, then one fp32 bias add.)
__global__ __launch_bounds__(256)
void chain_gemm_qk(const float* __restrict__ x, const float* __restrict__ W,
                   const float* __restrict__ bias, float* __restrict__ Out)
{
    const int tid  = threadIdx.x;
    const int col  = blockIdx.y * 256 + tid;        // 0..511
    const int row0 = blockIdx.x * 16;               // 16 rows per block

    float acc[16];
    #pragma unroll
    for (int r = 0; r < 16; ++r) acc[r] = 0.f;

    for (int k = 0; k < D_MODEL; k += 4) {          // one panel: k = 0..511
        const float w0 = W[(size_t)(k + 0) * D_MODEL + col];
        const float w1 = W[(size_t)(k + 1) * D_MODEL + col];
        const float w2 = W[(size_t)(k + 2) * D_MODEL + col];
        const float w3 = W[(size_t)(k + 3) * D_MODEL + col];
        #pragma unroll
        for (int r = 0; r < 16; ++r) {
            const float4 xv = *reinterpret_cast<const float4*>(
                &x[(size_t)(row0 + r) * D_MODEL + k]);
            acc[r] = __fmaf_rn(xv.x, w0, acc[r]);
            acc[r] = __fmaf_rn(xv.y, w1, acc[r]);
            acc[r] = __fmaf_rn(xv.z, w2, acc[r]);
            acc[r] = __fmaf_rn(xv.w, w3, acc[r]);
        }
    }

    const float bc = bias[col];
    const int h = col >> 6, d = col & 63;
    #pragma unroll
    for (int r = 0; r < 16; ++r) {
        const int row = row0 + r;
        const int b = row >> 11, l = row & (L_SEQ - 1);
        Out[((size_t)((b * NHEAD + h) * L_SEQ + l)) * DH + d] =
            __fadd_rn(acc[r], bc);
    }
}

// ---- attention: BLAS-chain scores (LOCKED bits) -> exact fp32 top-38 ----
// Perf deltas vs round 12 (arithmetic bit-identical):
//  * 512 threads / 8 waves, ONE query per wave: s[] halves to 32 regs ->
//    live set ~80 VGPR, fits the 128 cap with NO spill (r12 still wrote
//    ~512B/thread of scratch: WRITE_SIZE 1.06 GB vs 16.8 MB of ctx)
//  * __launch_bounds__(512,4): 4 waves/SIMD (2x r12's latency hiding)
//  * binary-search count via __ballot+__popcll: v_cmp + scalar s_bcnt1
//    (SALU pipe) instead of per-lane add + 6-shfl reduce -> selection
//    VALU cost drops ~4x
//  * ctx V-loads 8-deep pipelined (FMA chain still ascending i)
__global__ __launch_bounds__(512, 4)
void attn_kernel(const float* __restrict__ Q, const float* __restrict__ K,
                 const float* __restrict__ V, float* __restrict__ ctx)
{
    __shared__ float Qs[QPB][DH];          // 2 KB
    __shared__ float Ks[KT * DH];          // 32 KB, elem = r*64 + (col ^ ((r&7)<<2))
    __shared__ int   kidx[QPB][64];        // 2 KB  kept keys (ascending)
    __shared__ float kwgt[QPB][64];        // 2 KB  kept exp-weights

    // XCD swizzle: all 256 q-tiles of a (b,h) on one XCD (K/V L2-resident)
    const int bid = blockIdx.x;
    const int xcd = bid & 7, jrem = bid >> 3;
    const int bh  = xcd * 4 + (jrem >> 8);   // 0..31
    const int qt  = jrem & 255;              // 0..255
    const int b   = bh >> 3, h = bh & 7;

    const float* __restrict__ Qbh = Q + (size_t)bh * L_SEQ * DH;
    const float* __restrict__ Kbh = K + (size_t)bh * L_SEQ * DH;
    const float* __restrict__ Vbh = V + (size_t)bh * L_SEQ * DH;

    const int tid = threadIdx.x;
    const int wave = tid >> 6, lane = tid & 63;
    const int qg = wave;                     // one query per wave

    {   // stage Q tile (8x64): one float per thread, coalesced
        const int q = tid >> 6, d = tid & 63;
        Qs[q][d] = Qbh[(size_t)(qt * QPB + q) * DH + d];
    }

    float s[32];

    #pragma unroll
    for (int t = 0; t < L_SEQ / KT; ++t) {        // 16 tiles, fully unrolled
        __syncthreads();
        #pragma unroll
        for (int c = 0; c < 4; ++c) {             // stage K tile, swizzled
            const int f = c * 2048 + tid * 4;
            const int r = f >> 6, col = f & 63;
            const int sidx = (r << 6) + (col ^ ((r & 7) << 2));
            *reinterpret_cast<float4*>(&Ks[sidx]) =
                *reinterpret_cast<const float4*>(&Kbh[(size_t)t * (KT * DH) + f]);
        }
        __syncthreads();

        // single FMA chain over d ascending per key — LOCKED order
        float v0 = 0.f, v1 = 0.f;
        #pragma unroll
        for (int dc = 0; dc < 16; ++dc) {
            const int sw = (dc ^ (lane & 7)) << 2;   // logical cols 4dc..4dc+3
            const float4 k0 = *reinterpret_cast<const float4*>(
                &Ks[(lane << 6) + sw]);
            const float4 k1 = *reinterpret_cast<const float4*>(
                &Ks[((64 + lane) << 6) + sw]);
            const float4 p = *reinterpret_cast<const float4*>(&Qs[qg][dc << 2]);
            v0 = __fmaf_rn(p.x, k0.x, v0);
            v0 = __fmaf_rn(p.y, k0.y, v0);
            v0 = __fmaf_rn(p.z, k0.z, v0);
            v0 = __fmaf_rn(p.w, k0.w, v0);
            v1 = __fmaf_rn(p.x, k1.x, v1);
            v1 = __fmaf_rn(p.y, k1.y, v1);
            v1 = __fmaf_rn(p.z, k1.z, v1);
            v1 = __fmaf_rn(p.w, k1.w, v1);
        }
        // /sqrt(64) = *0.125, exact
        s[2*t]     = __fmul_rn(v0, 0.125f);
        s[2*t + 1] = __fmul_rn(v1, 0.125f);
    }

    // map scores to monotone uint space (in place)
    #pragma unroll
    for (int j = 0; j < 32; ++j)
        s[j] = __uint_as_float(mapmono(s[j]));

    // exact fp32 38th-largest: binary search in mapped-uint space.
    // count = sum_j popcount(ballot(u_j >= mid)) -> v_cmp + s_bcnt1 (SALU)
    unsigned long long lo = 0ull, hi = 0x100000000ull;
    while (hi - lo > 1ull) {
        const unsigned mid = (unsigned)((lo + hi) >> 1);
        int cnt = 0;
        #pragma unroll
        for (int j = 0; j < 32; ++j)
            cnt += (int)__popcll(__ballot(__float_as_uint(s[j]) >= mid));
        if (cnt >= U_TOP) lo = mid; else hi = mid;
    }
    const unsigned thrU = (unsigned)lo;     // mapped bits of the 38th value

    // row max in mapped space (top-1 always kept)
    unsigned um = 0u;
    #pragma unroll
    for (int j = 0; j < 32; ++j) {
        const unsigned ub = __float_as_uint(s[j]);
        um = um > ub ? um : ub;
    }
    #pragma unroll
    for (int off = 32; off; off >>= 1) {
        const unsigned o = (unsigned)__shfl_xor((int)um, off);
        um = um > o ? um : o;
    }
    const float mrow = __uint_as_float((um & 0x80000000u) ? (um & 0x7FFFFFFFu) : ~um);

    // compact kept keys (ascending key order) via ballot prefix-sum
    int base = 0; float lsum = 0.f;
    #pragma unroll
    for (int j = 0; j < 32; ++j) {
        const unsigned ub = __float_as_uint(s[j]);
        const bool keep = (ub >= thrU);     // == !(score < thr), np semantics
        const unsigned long long mk = __ballot(keep);
        if (keep) {
            const float sc = __uint_as_float((ub & 0x80000000u) ? (ub & 0x7FFFFFFFu) : ~ub);
            const float w = __expf(sc - mrow);
            const int pos = base + (int)__popcll(mk & ((1ull << lane) - 1ull));
            if (pos < 64) {
                kidx[qg][pos] = ((j >> 1) << 7) + ((j & 1) << 6) + lane;
                kwgt[qg][pos] = w;
            }
            lsum += w;
        }
        base += (int)__popcll(mk);
    }
    #pragma unroll
    for (int off = 32; off; off >>= 1) lsum += __shfl_xor(lsum, off);
    const int nk = base < 64 ? base : 64;

    // ctx[d] = (sum over kept, ascending key order) w * V[k][d] / Z
    // 8-deep load pipeline; FMA chain order preserved (ascending i)
    float acc = 0.f;
    int i = 0;
    for (; i + 8 <= nk; i += 8) {
        float wv[8], vv[8];
        #pragma unroll
        for (int u = 0; u < 8; ++u) {
            wv[u] = kwgt[qg][i + u];
            vv[u] = Vbh[(size_t)kidx[qg][i + u] * DH + lane];
        }
        #pragma unroll
        for (int u = 0; u < 8; ++u)
            acc = __fmaf_rn(wv[u], vv[u], acc);
    }
    for (; i < nk; ++i)
        acc = __fmaf_rn(kwgt[qg][i], Vbh[(size_t)kidx[qg][i] * DH + lane], acc);
    acc /= lsum;

    const int l = qt * QPB + qg;
    ctx[((size_t)(b * L_SEQ + l)) * D_MODEL + h * DH + lane] = acc;
}

extern "C" void kernel_launch(void* const* d_in, const int* in_sizes, int n_in,
                              void* d_out, int out_size, void* d_ws, size_t ws_size,
                              hipStream_t stream) {
    (void)in_sizes; (void)n_in; (void)out_size; (void)ws_size;
    const float* x  = (const float*)d_in[0];
    const float* Wq = (const float*)d_in[1];
    const float* bq = (const float*)d_in[2];
    const float* Wk = (const float*)d_in[3];
    const float* bk = (const float*)d_in[4];
    const float* Wv = (const float*)d_in[5];
    const float* bv = (const float*)d_in[6];
    const float* Wo = (const float*)d_in[7];
    const float* bo = (const float*)d_in[8];
    float* out = (float*)d_out;

    // ws: Qf | Kf | V | ctx = 4 x 16.78 MB = 67.1 MB
    const size_t NE = (size_t)B_SZ * NHEAD * L_SEQ * DH;   // 4.19e6
    float* Qf = (float*)d_ws;
    float* Kf = Qf + NE;
    float* Vw = Kf + NE;
    float* Cw = Vw + NE;

    const dim3 gq(512, 2), g(128, 8), blk(256);
    chain_gemm_qk<<<gq, blk, 0, stream>>>(x, Wq, bq, Qf);
    chain_gemm_qk<<<gq, blk, 0, stream>>>(x, Wk, bk, Kf);
    gemm512<1>   <<<g,  blk, 0, stream>>>(x, Wv, bv, Vw);
    attn_kernel  <<<dim3(8192), dim3(512), 0, stream>>>(Qf, Kf, Vw, Cw);
    gemm512<0>   <<<g,  blk, 0, stream>>>(Cw, Wo, bo, out);
}